// Round 19
// baseline (60.757 us; speedup 1.0000x reference)
//
#include <hip/hip_runtime.h>
#include <math.h>

#define BB 8
#define NN 2000
#define CC 81
#define NCLS 80             // classes 1..80 (class 0 never valid)
#define MAXI 100
#define MCLS 128            // 4 quarters x 32 = 128 member cap per class
#define QCAP 32             // per-quarter per-class cap (mean ~6.25, +10 sd)

static constexpr float kMinConf = 0.7f;
static constexpr float kNmsThr  = 0.3f;

// ---------------- workspace layout (bytes) ----------------
// boxes  : [0,       256000)   BN*4 f32 (refined, clipped)
// cls    : [256000,  320000)   BN i32   (argmax class; 0 if invalid)
// qcnt   : [320000,  330240)   8*80*4 i32 per-(batch,class,quarter) counts
//                              (plain stores every call; no zeroing needed)
// cslot  : [330240,  985600)   8*80*4*32 u64 member keys, per-quarter regions
// keysrc : [985600,  1113600)  BN u64 (kept key or 0; kA zeroes, kB1 writes)

// key = (score_bits << 32) | ~idx. Valid scores are positive floats so u32
// compare == float compare; key desc == (score desc, idx asc) == reference's
// stable descending argsort. idx = ~(u32)key. Keys unique; 0 = "absent".
__device__ __forceinline__ unsigned long long mkey(float s, int i) {
    return ((unsigned long long)__float_as_uint(s) << 32) | (unsigned int)(~(unsigned int)i);
}

__device__ __forceinline__ bool iou_gt_thr(float4 a, float aarea, float4 t) {
    float iy1 = fmaxf(a.x, t.x), ix1 = fmaxf(a.y, t.y);
    float iy2 = fminf(a.z, t.z), ix2 = fminf(a.w, t.w);
    float inter = fmaxf(iy2 - iy1, 0.f) * fmaxf(ix2 - ix1, 0.f);
    float tarea = (t.z - t.x) * (t.w - t.y);
    float uni = fmaxf(aarea + tarea - inter, 1e-12f);
    return inter > kNmsThr * uni;
}

// ---- kA: 32 blocks (batch-quarter) x 1024. Wave-per-ROI argmax + refine
// (R14-validated math); valid ROIs bucket into per-class LDS lists (LDS
// atomics, in-CU); publish to per-(b,c,q) PRIVATE slot regions with plain
// stores (no global atomics, no pre-zeroing). Also zeroes out+keysrc. ----
__global__ void __launch_bounds__(1024) kA_refine_bucket(
        const float* __restrict__ rois,
        const float* __restrict__ probs,
        const float* __restrict__ deltas,
        float* __restrict__ boxes,
        int* __restrict__ cls,
        int* __restrict__ qcnt,
        unsigned long long* __restrict__ cslot,
        unsigned long long* __restrict__ keysrc,
        float* __restrict__ outz) {
    const int b = blockIdx.x >> 2;
    const int q = blockIdx.x & 3;
    const int tid = threadIdx.x;
    const int w = tid >> 6;             // wave 0..15
    const int l = tid & 63;

    __shared__ unsigned long long lkey[NCLS][QCAP];  // 20 KB
    __shared__ int lcnt[NCLS];

    int gtid = blockIdx.x * 1024 + tid;              // 0..32767
    if (gtid < BB * MAXI * 6) outz[gtid] = 0.f;      // pre-zero output
    if (gtid < BB * NN) keysrc[gtid] = 0ull;         // zero kept-key array
    if (tid < NCLS) lcnt[tid] = 0;
    __syncthreads();

    // ---- wave-per-ROI argmax over this quarter's 500 rows ----
    for (int r = 0; r < 32; ++r) {
        int loc = r * 16 + w;                        // 0..511 (wave-uniform)
        if (loc >= 500) break;
        int i = q * 500 + loc;                       // row in batch
        int wid = b * NN + i;

        const float* p = probs + (size_t)wid * CC;
        float v1 = p[l];                             // l < 64 < 81 valid
        int   i1 = l;
        int   c2 = l + 64;
        float v2 = (c2 < CC) ? p[c2] : -1.0f;        // probs in [0,1)
        float bv; int bi;
        if (v2 > v1) { bv = v2; bi = c2; } else { bv = v1; bi = i1; }

        #pragma unroll
        for (int off = 32; off; off >>= 1) {
            float ov = __shfl_xor(bv, off);
            int   oi = __shfl_xor(bi, off);
            if (ov > bv || (ov == bv && oi < bi)) { bv = ov; bi = oi; }
        }

        if (l == 0) {
            const float4 dl = *(const float4*)(deltas + ((size_t)wid * CC + bi) * 4);
            float dy = dl.x * 0.1f, dx = dl.y * 0.1f, dh = dl.z * 0.2f, dw = dl.w * 0.2f;
            const float4 rr = *(const float4*)(rois + (size_t)wid * 4);
            float y1 = rr.x, x1 = rr.y, y2 = rr.z, x2 = rr.w;
            float h = y2 - y1, ww = x2 - x1;
            float cy = y1 + 0.5f * h + dy * h;
            float cx = x1 + 0.5f * ww + dx * ww;
            float h2 = h * expf(dh);
            float w2 = ww * expf(dw);
            float oy1 = fminf(fmaxf(cy - 0.5f * h2, 0.f), 1.f);
            float ox1 = fminf(fmaxf(cx - 0.5f * w2, 0.f), 1.f);
            float oy2 = fminf(fmaxf(cy + 0.5f * h2, 0.f), 1.f);
            float ox2 = fminf(fmaxf(cx + 0.5f * w2, 0.f), 1.f);
            bool valid = (bi > 0) && (bv >= kMinConf);
            float4 bx; bx.x = oy1; bx.y = ox1; bx.z = oy2; bx.w = ox2;
            ((float4*)boxes)[wid] = bx;
            cls[wid] = valid ? bi : 0;
            if (valid) {
                int cidx = bi - 1;
                int pos = atomicAdd(&lcnt[cidx], 1); // LDS atomic, in-CU
                if (pos < QCAP) lkey[cidx][pos] = mkey(bv, i);
            }
        }
    }
    __syncthreads();

    // ---- publish: plain stores to this quarter's private region ----
    if (tid < NCLS) qcnt[(b * NCLS + tid) * 4 + q] = min(lcnt[tid], QCAP);
    for (int e = tid; e < NCLS * QCAP; e += 1024) {
        int c = e >> 5, j = e & (QCAP - 1);
        if (j < min(lcnt[c], QCAP))
            cslot[(((size_t)b * NCLS + c) * 4 + q) * QCAP + j] = lkey[c][j];
    }
}

// ---- kB1: one 64-thread block per (batch,class). Concatenate the 4 quarter
// lists (<=32 each -> cnt <= 128), in-wave rank sort + ballot-fixpoint greedy
// NMS (validated exact); kept rows write their u64 key into keysrc[row]. ----
__global__ void __launch_bounds__(64) kB1_nms(
        const float* __restrict__ boxes,
        const int* __restrict__ qcnt,
        const unsigned long long* __restrict__ cslot,
        unsigned long long* __restrict__ keysrc) {
    const int p = blockIdx.x;
    const int b = p / NCLS;
    const int cidx = p % NCLS;
    const int l = threadIdx.x;

    __shared__ unsigned long long mk[MCLS];
    __shared__ float4 mbox[MCLS];

    const int* qc = qcnt + (b * NCLS + cidx) * 4;
    int qc0 = qc[0], qc1 = qc[1], qc2 = qc[2], qc3 = qc[3];   // scalar loads
    const int cnt = qc0 + qc1 + qc2 + qc3;                    // <= 128
    if (cnt == 0) return;
    int pref1 = qc0, pref2 = qc0 + qc1, pref3 = qc0 + qc1 + qc2;

    const unsigned long long* base = cslot + ((size_t)b * NCLS + cidx) * (4 * QCAP);
    const float4* bxs = (const float4*)boxes + (size_t)b * NN;

    // gather the 4 quarter lists compactly into mk
    #pragma unroll
    for (int e0 = 0; e0 < 2; ++e0) {
        int e = e0 * 64 + l;                         // 0..127
        int qq = e >> 5, j = e & (QCAP - 1);
        int qcv = (qq == 0) ? qc0 : (qq == 1) ? qc1 : (qq == 2) ? qc2 : qc3;
        int pr  = (qq == 0) ? 0   : (qq == 1) ? pref1 : (qq == 2) ? pref2 : pref3;
        if (j < qcv) mk[pr + j] = base[e];
    }

    // in-wave stable rank sort by key desc (lockstep wave: stores of the
    // gather complete before the sort's reads issue)
    unsigned long long va = (l < cnt) ? mk[l] : 0ull;
    unsigned long long vb = (64 + l < cnt) ? mk[64 + l] : 0ull;
    int ra = 0, rb = 0;
    for (int t = 0; t < cnt; ++t) {
        unsigned long long kt = mk[t];               // uniform LDS broadcast
        ra += (kt > va);
        rb += (kt > vb);
    }
    if (l < cnt) mk[ra] = va;
    if (64 + l < cnt) mk[rb] = vb;

    // fetch member boxes (sorted order)
    for (int t = l; t < cnt; t += 64) {
        int i = (int)(~(unsigned int)mk[t]);
        mbox[t] = bxs[i];
    }

    // chunk 0: ballot fixpoint == greedy (validated exact)
    unsigned long long kept0 = 0ull;
    {
        bool act = (l < cnt);
        float4 a = mbox[act ? l : 0];
        float aarea = (a.z - a.x) * (a.w - a.y);
        unsigned long long colmask = 0ull;
        int tend = min(64, cnt);
        for (int t = 0; t < tend; ++t) {
            float4 tb = mbox[t];                     // uniform LDS broadcast
            if (t < l && act && iou_gt_thr(a, aarea, tb)) colmask |= (1ull << t);
        }
        unsigned long long kept = __ballot(act);
        while (true) {
            bool alive = act && ((colmask & kept) == 0ull);
            unsigned long long k2m = __ballot(alive);
            if (k2m == kept) break;
            kept = k2m;
        }
        kept0 = kept;
        bool alive = act && ((colmask & kept0) == 0ull);
        if (alive) {
            unsigned long long myk = mk[l];
            keysrc[(size_t)b * NN + (int)(~(unsigned int)myk)] = myk;
        }
    }
    // chunk 1 (members 64..cnt-1): rare
    if (cnt > 64) {
        int m = 64 + l;
        bool act = (m < cnt);
        float4 a = mbox[act ? m : 0];
        float aarea = (a.z - a.x) * (a.w - a.y);
        bool presup = false;
        for (int t = 0; t < 64; ++t) {
            if ((kept0 >> t) & 1ull) {
                if (act && iou_gt_thr(a, aarea, mbox[t])) presup = true;
            }
        }
        unsigned long long colmask = 0ull;
        for (int t = 64; t < cnt; ++t) {
            float4 tb = mbox[t];
            if ((t - 64) < l && act && iou_gt_thr(a, aarea, tb)) colmask |= (1ull << (t - 64));
        }
        bool pre = act && !presup;
        unsigned long long kept = __ballot(pre);
        while (true) {
            bool alive = pre && ((colmask & kept) == 0ull);
            unsigned long long k2m = __ballot(alive);
            if (k2m == kept) break;
            kept = k2m;
        }
        bool alive = pre && ((colmask & kept) == 0ull);
        if (alive) {
            unsigned long long myk = mk[64 + l];
            keysrc[(size_t)b * NN + (int)(~(unsigned int)myk)] = myk;
        }
    }
}

// ---- kC: 1 block per batch x 1024. Positional keys from keysrc (coalesced),
// histogram threshold, candidate rank-count, write. (R14/R18-validated) ----
__global__ void __launch_bounds__(1024) kC_emit(
        const unsigned long long* __restrict__ keysrc,
        const float* __restrict__ boxes,
        const int* __restrict__ cls,
        float* __restrict__ out) {
    const int b = blockIdx.x;
    const int tid = threadIdx.x;
    const int wv = tid >> 6;
    const int l = tid & 63;

    __shared__ ulonglong2 keys2[1024];               // 16 KB (positional by row)
    __shared__ ulonglong2 cand2[256];                //  4 KB
    __shared__ int hist[256];
    __shared__ int Tcnt, tbsh, candn;
    unsigned long long* keys = (unsigned long long*)keys2;
    unsigned long long* cand = (unsigned long long*)cand2;

    if (tid < 256) hist[tid] = 0;
    if (tid < 48) keys[2000 + tid] = 0ull;           // pad tail
    if (tid == 0) { Tcnt = 0; candn = 0; }
    __syncthreads();

    const float4* bxs = (const float4*)boxes + (size_t)b * NN;

    for (int i = tid; i < NN; i += 1024) {
        unsigned long long kv = keysrc[(size_t)b * NN + i];
        keys[i] = kv;
        bool f = (kv != 0ull);
        if (f) atomicAdd(&hist[(int)((kv >> 47) & 0xFF)], 1);
        unsigned long long m = __ballot(f);
        if (l == 0 && m) atomicAdd(&Tcnt, __popcll(m));
    }
    __syncthreads();
    const int T = Tcnt;
    if (T == 0) return;                              // out pre-zeroed by kA

    // wave 0: threshold bucket tb (kept scores in [0.7,1) -> fixed exponent ->
    // bucket (key>>47)&0xFF monotone in score)
    if (wv == 0) {
        int cum = 0, tb = 0, done = 0;
        for (int chunk = 3; chunk >= 0 && !done; --chunk) {
            int bkt = chunk * 64 + (63 - l);         // lane 0 = highest bucket
            int s = hist[bkt];
            #pragma unroll
            for (int off = 1; off < 64; off <<= 1) {
                int o = __shfl_up(s, off);
                if (l >= off) s += o;
            }
            int chunktot = __shfl(s, 63);
            if (cum + chunktot >= MAXI) {
                unsigned long long m = __ballot(cum + s >= MAXI);
                int lane = __ffsll((long long)m) - 1;
                tb = chunk * 64 + (63 - lane);
                done = 1;
            } else {
                cum += chunktot;
            }
        }
        if (l == 0) tbsh = done ? tb : 0;            // T<100 -> all buckets
    }
    __syncthreads();
    const int tb = tbsh;

    // compact candidates (bucket >= tb); rank among candidates == global rank
    for (int i = tid; i < NN; i += 1024) {
        unsigned long long kv = keys[i];
        bool pr = (kv != 0ull) && ((int)((kv >> 47) & 0xFF) >= tb);
        unsigned long long m = __ballot(pr);
        int basew = 0;
        if (l == 0 && m) basew = atomicAdd(&candn, __popcll(m));
        basew = __shfl(basew, 0);
        if (pr) {
            int pos = basew + __popcll(m & ((1ull << l) - 1ull));
            if (pos < 512) cand[pos] = kv;
        }
    }
    __syncthreads();
    const int nc = candn;
    if (tid == 0 && nc < 512) cand[nc] = 0ull;       // pad for pair read
    __syncthreads();

    if (nc <= 512) {
        const int np = (nc + 1) >> 1;
        for (int s = tid; s < nc; s += 1024) {
            unsigned long long myk = cand[s];
            int r = 0;
            for (int t = 0; t < np; ++t) {
                ulonglong2 kv = cand2[t];
                r += (int)(kv.x > myk);
                r += (int)(kv.y > myk);              // pad 0 never counts
            }
            if (r < MAXI) {
                int i = (int)(~(unsigned int)myk);
                float4 bx = bxs[i];
                float* o = out + ((size_t)b * MAXI + r) * 6;
                o[0] = bx.x; o[1] = bx.y; o[2] = bx.z; o[3] = bx.w;
                o[4] = (float)cls[(size_t)b * NN + i];
                o[5] = __uint_as_float((unsigned int)(myk >> 32));
            }
        }
    } else {
        // pathological fallback: rank over all rows (zeros excluded)
        for (int s = tid; s < NN; s += 1024) {
            unsigned long long myk = keys[s];
            if (myk == 0ull) continue;
            int r = 0;
            for (int t = 0; t < 1024; ++t) {
                ulonglong2 kv = keys2[t];
                r += (int)(kv.x > myk);
                r += (int)(kv.y > myk);
            }
            if (r < MAXI) {
                int i = (int)(~(unsigned int)myk);
                float4 bx = bxs[i];
                float* o = out + ((size_t)b * MAXI + r) * 6;
                o[0] = bx.x; o[1] = bx.y; o[2] = bx.z; o[3] = bx.w;
                o[4] = (float)cls[(size_t)b * NN + i];
                o[5] = __uint_as_float((unsigned int)(myk >> 32));
            }
        }
    }
}

extern "C" void kernel_launch(void* const* d_in, const int* in_sizes, int n_in,
                              void* d_out, int out_size, void* d_ws, size_t ws_size,
                              hipStream_t stream) {
    const float* rois   = (const float*)d_in[0];
    const float* probs  = (const float*)d_in[1];
    const float* deltas = (const float*)d_in[2];
    float* outp = (float*)d_out;

    char* ws = (char*)d_ws;
    float* boxes = (float*)(ws + 0);
    int*   cls   = (int*)  (ws + 256000);
    int*   qcnt  = (int*)  (ws + 320000);
    unsigned long long* cslot  = (unsigned long long*)(ws + 330240);
    unsigned long long* keysrc = (unsigned long long*)(ws + 985600);

    kA_refine_bucket<<<BB * 4, 1024, 0, stream>>>(rois, probs, deltas, boxes,
                                                  cls, qcnt, cslot, keysrc, outp);
    kB1_nms<<<BB * NCLS, 64, 0, stream>>>(boxes, qcnt, cslot, keysrc);
    kC_emit<<<BB, 1024, 0, stream>>>(keysrc, boxes, cls, outp);
}

// Round 20
// 38.480 us; speedup vs baseline: 1.5790x; 1.5790x over previous
//
#include <hip/hip_runtime.h>
#include <math.h>

#define BB 8
#define NN 2000
#define CC 81
#define NCLS 80             // classes 1..80 (class 0 never valid)
#define MAXI 100
#define MCLS 128            // per-class member cap (mean ~25, sd ~5)
#define WCAP 128            // per-wave collect cap

static constexpr float kMinConf = 0.7f;
static constexpr float kNmsThr  = 0.3f;

// ---------------- workspace layout (bytes) ----------------
// boxes  : [0,      256000)   BN*4 f32 (refined, clipped)
// sc     : [256000, 320000)   BN f32   (raw max score)
// cls    : [320000, 384000)   BN i32   (argmax class; 0 if invalid)
// keysrc : [384000, 512000)   BN u64   (kept key or 0; kA zeroes, kB writes)

// key = (score_bits << 32) | ~idx. Valid scores are positive floats so u32
// compare == float compare; key desc == (score desc, idx asc) == reference's
// stable descending argsort. idx = ~(u32)key. Keys unique; 0 = "absent".
__device__ __forceinline__ unsigned long long mkey(float s, int i) {
    return ((unsigned long long)__float_as_uint(s) << 32) | (unsigned int)(~(unsigned int)i);
}

__device__ __forceinline__ bool iou_gt_thr(float4 a, float aarea, float4 t) {
    float iy1 = fmaxf(a.x, t.x), ix1 = fmaxf(a.y, t.y);
    float iy2 = fminf(a.z, t.z), ix2 = fminf(a.w, t.w);
    float inter = fmaxf(iy2 - iy1, 0.f) * fmaxf(ix2 - ix1, 0.f);
    float tarea = (t.z - t.x) * (t.w - t.y);
    float uni = fmaxf(aarea + tarea - inter, 1e-12f);
    return inter > kNmsThr * uni;
}

// ---- kA: wave-per-ROI argmax + box refine (4000 blocks — WIDE); zero out[]
// and keysrc[]. No atomics. (R13-measured ~3.3 us) ----
__global__ void kA_refine(const float* __restrict__ rois,
                          const float* __restrict__ probs,
                          const float* __restrict__ deltas,
                          float* __restrict__ boxes,
                          float* __restrict__ sc,
                          int* __restrict__ cls,
                          unsigned long long* __restrict__ keysrc,
                          float* __restrict__ outz) {
    int gtid = blockIdx.x * blockDim.x + threadIdx.x;
    if (gtid < BB * MAXI * 6) outz[gtid] = 0.f;      // pre-zero output
    if (gtid < BB * NN) keysrc[gtid] = 0ull;         // zero kept-key array

    int wid = gtid >> 6;                // one wave per ROI
    int l = gtid & 63;

    const float* p = probs + (size_t)wid * CC;
    float v1 = p[l];                    // l < 64 < 81 always valid
    int   i1 = l;
    int   c2 = l + 64;
    float v2 = (c2 < CC) ? p[c2] : -1.0f;   // probs in [0,1)
    float bv; int bi;
    if (v2 > v1) { bv = v2; bi = c2; } else { bv = v1; bi = i1; }

    #pragma unroll
    for (int off = 32; off; off >>= 1) {
        float ov = __shfl_xor(bv, off);
        int   oi = __shfl_xor(bi, off);
        if (ov > bv || (ov == bv && oi < bi)) { bv = ov; bi = oi; }
    }

    if (l == 0) {
        const float4 dl = *(const float4*)(deltas + ((size_t)wid * CC + bi) * 4);
        float dy = dl.x * 0.1f, dx = dl.y * 0.1f, dh = dl.z * 0.2f, dw = dl.w * 0.2f;
        const float4 r = *(const float4*)(rois + (size_t)wid * 4);
        float y1 = r.x, x1 = r.y, y2 = r.z, x2 = r.w;
        float h = y2 - y1, w = x2 - x1;
        float cy = y1 + 0.5f * h + dy * h;
        float cx = x1 + 0.5f * w + dx * w;
        float h2 = h * expf(dh);
        float w2 = w * expf(dw);
        float oy1 = fminf(fmaxf(cy - 0.5f * h2, 0.f), 1.f);
        float ox1 = fminf(fmaxf(cx - 0.5f * w2, 0.f), 1.f);
        float oy2 = fminf(fmaxf(cy + 0.5f * h2, 0.f), 1.f);
        float ox2 = fminf(fmaxf(cx + 0.5f * w2, 0.f), 1.f);
        bool valid = (bi > 0) && (bv >= kMinConf);
        float4 bx; bx.x = oy1; bx.y = ox1; bx.z = oy2; bx.w = ox2;
        ((float4*)boxes)[wid] = bx;
        sc[wid] = bv;
        cls[wid] = valid ? bi : 0;      // cls==0 encodes "invalid"
    }
}

// ---- kB: one 256-thread block per (batch,class) (640 blocks — WIDE).
// 4 waves scan 500-row quarters collecting class members (R14-validated),
// merge via LDS prefix; wave 0 runs sort + ballot-fixpoint greedy NMS
// (validated exact); kept rows write their u64 key into keysrc[row]. ----
__global__ void __launch_bounds__(256) kB_nms(
        const float* __restrict__ boxes,
        const float* __restrict__ sc,
        const int* __restrict__ cls,
        unsigned long long* __restrict__ keysrc) {
    const int p = blockIdx.x;
    const int b = p / NCLS;
    const int cidx = p % NCLS;
    const int c = cidx + 1;             // classes 1..80
    const int tid = threadIdx.x;
    const int wv = tid >> 6;
    const int l = tid & 63;

    __shared__ unsigned long long wlist[4][WCAP];   // 4 KB
    __shared__ int wcnt[4];
    __shared__ unsigned long long mk[MCLS];         // 1 KB
    __shared__ float4 mbox[MCLS];                   // 2 KB

    const int* cl = cls + (size_t)b * NN;
    const float* ssc = sc + (size_t)b * NN;
    const float4* bxs = (const float4*)boxes + (size_t)b * NN;

    // parallel collect: wave wv scans rows [wv*500, wv*500+500)
    {
        int cnt = 0;
        const int base_row = wv * 500;
        for (int ch = 0; ch < 8; ++ch) {
            int idx = ch * 64 + l;                   // 0..511
            bool inq = idx < 500;
            int r = base_row + idx;
            int ci = inq ? cl[r] : 0;
            bool pred = (ci == c);
            unsigned long long mask = __ballot(pred);
            if (pred) {
                int pos = cnt + __popcll(mask & ((1ull << l) - 1ull));
                if (pos < WCAP) wlist[wv][pos] = mkey(ssc[r], r);
            }
            cnt += __popcll(mask);
        }
        if (l == 0) wcnt[wv] = (cnt > WCAP) ? WCAP : cnt;
    }
    __syncthreads();

    // merge wave lists into mk (order irrelevant; sort is total on unique keys)
    int b0 = wcnt[0], b1 = wcnt[1], b2 = wcnt[2], b3 = wcnt[3];
    int myofs = (wv > 0 ? b0 : 0) + (wv > 1 ? b1 : 0) + (wv > 2 ? b2 : 0);
    int myn = wcnt[wv];
    int cnt_all = b0 + b1 + b2 + b3;
    if (cnt_all > MCLS) cnt_all = MCLS;
    if (l < myn && myofs + l < MCLS) mk[myofs + l] = wlist[wv][l];
    if (64 + l < myn && myofs + 64 + l < MCLS) mk[myofs + 64 + l] = wlist[wv][64 + l];
    __syncthreads();

    if (wv != 0) return;                             // no further barriers
    if (cnt_all == 0) return;
    const int cnt = cnt_all;

    // in-wave stable rank sort by key desc (two keys per lane)
    {
        unsigned long long Ka = (l < cnt) ? mk[l] : 0ull;
        unsigned long long Kb = (64 + l < cnt) ? mk[64 + l] : 0ull;
        int ra = 0, rb = 0;
        for (int t = 0; t < cnt; ++t) {
            unsigned long long kt = mk[t];           // uniform LDS broadcast
            ra += (kt > Ka);
            rb += (kt > Kb);
        }
        if (l < cnt) mk[ra] = Ka;
        if (64 + l < cnt) mk[rb] = Kb;
    }

    // fetch member boxes (sorted order)
    for (int t = l; t < cnt; t += 64) {
        int i = (int)(~(unsigned int)mk[t]);
        mbox[t] = bxs[i];
    }

    // chunk 0: ballot fixpoint == greedy (validated exact)
    unsigned long long kept0 = 0ull;
    {
        bool act = (l < cnt);
        float4 a = mbox[act ? l : 0];
        float aarea = (a.z - a.x) * (a.w - a.y);
        unsigned long long colmask = 0ull;
        int tend = min(64, cnt);
        for (int t = 0; t < tend; ++t) {
            float4 tb = mbox[t];                     // uniform LDS broadcast
            if (t < l && act && iou_gt_thr(a, aarea, tb)) colmask |= (1ull << t);
        }
        unsigned long long kept = __ballot(act);
        while (true) {
            bool alive = act && ((colmask & kept) == 0ull);
            unsigned long long k2m = __ballot(alive);
            if (k2m == kept) break;
            kept = k2m;
        }
        kept0 = kept;
        bool alive = act && ((colmask & kept0) == 0ull);
        if (alive) {
            unsigned long long myk = mk[l];
            keysrc[(size_t)b * NN + (int)(~(unsigned int)myk)] = myk;
        }
    }
    // chunk 1 (members 64..cnt-1): rare
    if (cnt > 64) {
        int m = 64 + l;
        bool act = (m < cnt);
        float4 a = mbox[act ? m : 0];
        float aarea = (a.z - a.x) * (a.w - a.y);
        bool presup = false;
        for (int t = 0; t < 64; ++t) {
            if ((kept0 >> t) & 1ull) {
                if (act && iou_gt_thr(a, aarea, mbox[t])) presup = true;
            }
        }
        unsigned long long colmask = 0ull;
        for (int t = 64; t < cnt; ++t) {
            float4 tb = mbox[t];
            if ((t - 64) < l && act && iou_gt_thr(a, aarea, tb)) colmask |= (1ull << (t - 64));
        }
        bool pre = act && !presup;
        unsigned long long kept = __ballot(pre);
        while (true) {
            bool alive = pre && ((colmask & kept) == 0ull);
            unsigned long long k2m = __ballot(alive);
            if (k2m == kept) break;
            kept = k2m;
        }
        bool alive = pre && ((colmask & kept) == 0ull);
        if (alive) {
            unsigned long long myk = mk[64 + l];
            keysrc[(size_t)b * NN + (int)(~(unsigned int)myk)] = myk;
        }
    }
}

// ---- kC: 256 blocks (8 batches x 32 slices) x 256 threads — WIDE. Each
// block redundantly: load batch keys (coalesced), histogram, threshold,
// compact candidates (deterministic SET; order may differ). Then rank+write
// only candidates with row%32 == slice — an exact identity-partition, so
// coverage and dedup hold regardless of per-block cand order. ----
__global__ void __launch_bounds__(256) kC_emit(
        const unsigned long long* __restrict__ keysrc,
        const float* __restrict__ boxes,
        const int* __restrict__ cls,
        float* __restrict__ out) {
    const int b = blockIdx.x >> 5;
    const int q = blockIdx.x & 31;
    const int tid = threadIdx.x;
    const int wv = tid >> 6;
    const int l = tid & 63;

    __shared__ ulonglong2 keys2[1024];               // 16 KB (positional by row)
    __shared__ ulonglong2 cand2[256];                //  4 KB
    __shared__ int hist[256];
    __shared__ int Tcnt, tbsh, candn;
    unsigned long long* keys = (unsigned long long*)keys2;
    unsigned long long* cand = (unsigned long long*)cand2;

    hist[tid] = 0;
    if (tid < 48) keys[2000 + tid] = 0ull;           // pad tail
    if (tid == 0) { Tcnt = 0; candn = 0; }
    __syncthreads();

    const float4* bxs = (const float4*)boxes + (size_t)b * NN;

    // load keys positionally + histogram + count (8 coalesced iterations)
    for (int i = tid; i < NN; i += 256) {
        unsigned long long kv = keysrc[(size_t)b * NN + i];
        keys[i] = kv;
        bool f = (kv != 0ull);
        if (f) atomicAdd(&hist[(int)((kv >> 47) & 0xFF)], 1);
        unsigned long long m = __ballot(f);
        if (l == 0 && m) atomicAdd(&Tcnt, __popcll(m));
    }
    __syncthreads();
    const int T = Tcnt;
    if (T == 0) return;                              // out pre-zeroed by kA

    // wave 0: threshold bucket tb (kept scores in [0.7,1) -> fixed exponent ->
    // bucket (key>>47)&0xFF monotone in score). Deterministic across blocks.
    if (wv == 0) {
        int cum = 0, tb = 0, done = 0;
        for (int chunk = 3; chunk >= 0 && !done; --chunk) {
            int bkt = chunk * 64 + (63 - l);         // lane 0 = highest bucket
            int s = hist[bkt];
            #pragma unroll
            for (int off = 1; off < 64; off <<= 1) {
                int o = __shfl_up(s, off);
                if (l >= off) s += o;
            }
            int chunktot = __shfl(s, 63);
            if (cum + chunktot >= MAXI) {
                unsigned long long m = __ballot(cum + s >= MAXI);
                int lane = __ffsll((long long)m) - 1;
                tb = chunk * 64 + (63 - lane);
                done = 1;
            } else {
                cum += chunktot;
            }
        }
        if (l == 0) tbsh = done ? tb : 0;            // T<100 -> all buckets
    }
    __syncthreads();
    const int tb = tbsh;

    // compact candidates (bucket >= tb); SET deterministic, order not (ok:
    // rank is computed against the whole set; slice selection is by row id)
    for (int i = tid; i < NN; i += 256) {
        unsigned long long kv = keys[i];
        bool pr = (kv != 0ull) && ((int)((kv >> 47) & 0xFF) >= tb);
        unsigned long long m = __ballot(pr);
        int basew = 0;
        if (l == 0 && m) basew = atomicAdd(&candn, __popcll(m));
        basew = __shfl(basew, 0);
        if (pr) {
            int pos = basew + __popcll(m & ((1ull << l) - 1ull));
            if (pos < 512) cand[pos] = kv;
        }
    }
    __syncthreads();
    const int nc = candn;
    if (tid == 0 && nc < 512) cand[nc] = 0ull;       // pad for pair read
    __syncthreads();

    if (nc <= 512) {
        // rank-count among candidates; process only rows of THIS slice
        const int np = (nc + 1) >> 1;
        for (int s = tid; s < nc; s += 256) {
            unsigned long long myk = cand[s];
            int i = (int)(~(unsigned int)myk);
            if ((i & 31) != q) continue;             // identity partition
            int r = 0;
            for (int t = 0; t < np; ++t) {
                ulonglong2 kv = cand2[t];
                r += (int)(kv.x > myk);
                r += (int)(kv.y > myk);              // pad 0 never counts
            }
            if (r < MAXI) {
                float4 bx = bxs[i];
                float* o = out + ((size_t)b * MAXI + r) * 6;
                o[0] = bx.x; o[1] = bx.y; o[2] = bx.z; o[3] = bx.w;
                o[4] = (float)cls[(size_t)b * NN + i];
                o[5] = __uint_as_float((unsigned int)(myk >> 32));
            }
        }
    } else {
        // pathological fallback: rank over all rows (zeros excluded), sliced
        for (int s = tid; s < NN; s += 256) {
            unsigned long long myk = keys[s];
            if (myk == 0ull) continue;
            if ((s & 31) != q) continue;
            int r = 0;
            for (int t = 0; t < 1024; ++t) {
                ulonglong2 kv = keys2[t];
                r += (int)(kv.x > myk);
                r += (int)(kv.y > myk);
            }
            if (r < MAXI) {
                float4 bx = bxs[s];
                float* o = out + ((size_t)b * MAXI + r) * 6;
                o[0] = bx.x; o[1] = bx.y; o[2] = bx.z; o[3] = bx.w;
                o[4] = (float)cls[(size_t)b * NN + s];
                o[5] = __uint_as_float((unsigned int)(myk >> 32));
            }
        }
    }
}

extern "C" void kernel_launch(void* const* d_in, const int* in_sizes, int n_in,
                              void* d_out, int out_size, void* d_ws, size_t ws_size,
                              hipStream_t stream) {
    const float* rois   = (const float*)d_in[0];
    const float* probs  = (const float*)d_in[1];
    const float* deltas = (const float*)d_in[2];
    float* outp = (float*)d_out;

    char* ws = (char*)d_ws;
    float* boxes = (float*)(ws + 0);
    float* sc    = (float*)(ws + 256000);
    int*   cls   = (int*)  (ws + 320000);
    unsigned long long* keysrc = (unsigned long long*)(ws + 384000);

    {
        int blocks = (BB * NN * 64) / 256;   // one wave per ROI, exact (WIDE)
        kA_refine<<<blocks, 256, 0, stream>>>(rois, probs, deltas, boxes, sc,
                                              cls, keysrc, outp);
    }
    kB_nms<<<BB * NCLS, 256, 0, stream>>>(boxes, sc, cls, keysrc);
    kC_emit<<<BB * 32, 256, 0, stream>>>(keysrc, boxes, cls, outp);
}

// Round 21
// 28.873 us; speedup vs baseline: 2.1043x; 1.3327x over previous
//
#include <hip/hip_runtime.h>
#include <math.h>

#define BB 8
#define NN 2000
#define CC 81
#define NCLS 80             // classes 1..80 (class 0 never valid)
#define MAXI 100
#define MCLS 128            // 4 quarters x 32 = 128 member cap per class
#define QCAP 32             // per-quarter per-class cap (mean ~6.25, +10 sd)

static constexpr float kMinConf = 0.7f;
static constexpr float kNmsThr  = 0.3f;

// ---------------- workspace layout (bytes) ----------------
// boxes  : [0,       256000)   BN*4 f32 (refined, clipped)
// sc     : [256000,  320000)   BN f32   (raw max score)
// cls    : [320000,  384000)   BN i32   (argmax class; 0 if invalid)
// qcnt   : [384000,  394240)   8*80*4 i32 per-(batch,class,quarter) counts
//                              (written unconditionally -> no zeroing)
// cslot  : [394240,  1049600)  8*80*4*32 u64 member keys, quarter-private
// keysrc : [1049600, 1177600)  BN u64 (kept key or 0; kA zeroes, kB1 writes)

// key = (score_bits << 32) | ~idx. Valid scores are positive floats so u32
// compare == float compare; key desc == (score desc, idx asc) == reference's
// stable descending argsort. idx = ~(u32)key. Keys unique; 0 = "absent".
__device__ __forceinline__ unsigned long long mkey(float s, int i) {
    return ((unsigned long long)__float_as_uint(s) << 32) | (unsigned int)(~(unsigned int)i);
}

__device__ __forceinline__ bool iou_gt_thr(float4 a, float aarea, float4 t) {
    float iy1 = fmaxf(a.x, t.x), ix1 = fmaxf(a.y, t.y);
    float iy2 = fminf(a.z, t.z), ix2 = fminf(a.w, t.w);
    float inter = fmaxf(iy2 - iy1, 0.f) * fmaxf(ix2 - ix1, 0.f);
    float tarea = (t.z - t.x) * (t.w - t.y);
    float uni = fmaxf(aarea + tarea - inter, 1e-12f);
    return inter > kNmsThr * uni;
}

// ---- kA: wave-per-ROI argmax + box refine (4000 blocks — WIDE); zero out[]
// and keysrc[]. No atomics. (R13-measured ~3.3 us; R18-validated) ----
__global__ void kA_refine(const float* __restrict__ rois,
                          const float* __restrict__ probs,
                          const float* __restrict__ deltas,
                          float* __restrict__ boxes,
                          float* __restrict__ sc,
                          int* __restrict__ cls,
                          unsigned long long* __restrict__ keysrc,
                          float* __restrict__ outz) {
    int gtid = blockIdx.x * blockDim.x + threadIdx.x;
    if (gtid < BB * MAXI * 6) outz[gtid] = 0.f;      // pre-zero output
    if (gtid < BB * NN) keysrc[gtid] = 0ull;         // zero kept-key array

    int wid = gtid >> 6;                // one wave per ROI
    int l = gtid & 63;

    const float* p = probs + (size_t)wid * CC;
    float v1 = p[l];                    // l < 64 < 81 always valid
    int   i1 = l;
    int   c2 = l + 64;
    float v2 = (c2 < CC) ? p[c2] : -1.0f;   // probs in [0,1)
    float bv; int bi;
    if (v2 > v1) { bv = v2; bi = c2; } else { bv = v1; bi = i1; }

    #pragma unroll
    for (int off = 32; off; off >>= 1) {
        float ov = __shfl_xor(bv, off);
        int   oi = __shfl_xor(bi, off);
        if (ov > bv || (ov == bv && oi < bi)) { bv = ov; bi = oi; }
    }

    if (l == 0) {
        const float4 dl = *(const float4*)(deltas + ((size_t)wid * CC + bi) * 4);
        float dy = dl.x * 0.1f, dx = dl.y * 0.1f, dh = dl.z * 0.2f, dw = dl.w * 0.2f;
        const float4 r = *(const float4*)(rois + (size_t)wid * 4);
        float y1 = r.x, x1 = r.y, y2 = r.z, x2 = r.w;
        float h = y2 - y1, w = x2 - x1;
        float cy = y1 + 0.5f * h + dy * h;
        float cx = x1 + 0.5f * w + dx * w;
        float h2 = h * expf(dh);
        float w2 = w * expf(dw);
        float oy1 = fminf(fmaxf(cy - 0.5f * h2, 0.f), 1.f);
        float ox1 = fminf(fmaxf(cx - 0.5f * w2, 0.f), 1.f);
        float oy2 = fminf(fmaxf(cy + 0.5f * h2, 0.f), 1.f);
        float ox2 = fminf(fmaxf(cx + 0.5f * w2, 0.f), 1.f);
        bool valid = (bi > 0) && (bv >= kMinConf);
        float4 bx; bx.x = oy1; bx.y = ox1; bx.z = oy2; bx.w = ox2;
        ((float4*)boxes)[wid] = bx;
        sc[wid] = bv;
        cls[wid] = valid ? bi : 0;      // cls==0 encodes "invalid"
    }
}

// ---- kB0: 32 blocks (batch-quarter) x 1024. One coalesced pass over this
// quarter's 500 rows; LDS-atomic bucketing into per-class lists; publish to
// quarter-PRIVATE slot regions with plain stores (no global atomics, no
// zeroing — counts written unconditionally every call). ----
__global__ void __launch_bounds__(1024) kB0_bucket(
        const float* __restrict__ sc,
        const int* __restrict__ cls,
        int* __restrict__ qcnt,
        unsigned long long* __restrict__ cslot) {
    const int b = blockIdx.x >> 2;
    const int q = blockIdx.x & 3;
    const int tid = threadIdx.x;

    __shared__ unsigned long long lkey[NCLS][QCAP];  // 20 KB
    __shared__ int lcnt[NCLS];

    if (tid < NCLS) lcnt[tid] = 0;
    __syncthreads();

    if (tid < 500) {
        int i = q * 500 + tid;                       // row in batch
        int c = cls[(size_t)b * NN + i];             // coalesced
        if (c > 0) {
            int pos = atomicAdd(&lcnt[c - 1], 1);    // LDS atomic, in-CU
            if (pos < QCAP) lkey[c - 1][pos] = mkey(sc[(size_t)b * NN + i], i);
        }
    }
    __syncthreads();

    if (tid < NCLS) qcnt[(b * NCLS + tid) * 4 + q] = min(lcnt[tid], QCAP);
    for (int e = tid; e < NCLS * QCAP; e += 1024) {
        int c = e >> 5, j = e & (QCAP - 1);
        if (j < min(lcnt[c], QCAP))
            cslot[(((size_t)b * NCLS + c) * 4 + q) * QCAP + j] = lkey[c][j];
    }
}

// ---- kB1: one 64-thread block per (batch,class) (640 blocks — WIDE).
// Concatenate the 4 quarter lists (R19-validated gather), in-wave rank sort
// + ballot-fixpoint greedy NMS (validated exact); kept rows write their u64
// key into keysrc[row]. ----
__global__ void __launch_bounds__(64) kB1_nms(
        const float* __restrict__ boxes,
        const int* __restrict__ qcnt,
        const unsigned long long* __restrict__ cslot,
        unsigned long long* __restrict__ keysrc) {
    const int p = blockIdx.x;
    const int b = p / NCLS;
    const int cidx = p % NCLS;
    const int l = threadIdx.x;

    __shared__ unsigned long long mk[MCLS];
    __shared__ float4 mbox[MCLS];

    const int* qc = qcnt + (b * NCLS + cidx) * 4;
    int qc0 = qc[0], qc1 = qc[1], qc2 = qc[2], qc3 = qc[3];   // scalar loads
    const int cnt = qc0 + qc1 + qc2 + qc3;                    // <= 128
    if (cnt == 0) return;
    int pref1 = qc0, pref2 = qc0 + qc1, pref3 = qc0 + qc1 + qc2;

    const unsigned long long* base = cslot + ((size_t)b * NCLS + cidx) * (4 * QCAP);
    const float4* bxs = (const float4*)boxes + (size_t)b * NN;

    // gather the 4 quarter lists compactly into mk (R19-validated)
    #pragma unroll
    for (int e0 = 0; e0 < 2; ++e0) {
        int e = e0 * 64 + l;                         // 0..127
        int qq = e >> 5, j = e & (QCAP - 1);
        int qcv = (qq == 0) ? qc0 : (qq == 1) ? qc1 : (qq == 2) ? qc2 : qc3;
        int pr  = (qq == 0) ? 0   : (qq == 1) ? pref1 : (qq == 2) ? pref2 : pref3;
        if (j < qcv) mk[pr + j] = base[e];
    }

    // in-wave stable rank sort by key desc (lockstep wave: gather stores
    // complete before the sort's reads issue)
    unsigned long long va = (l < cnt) ? mk[l] : 0ull;
    unsigned long long vb = (64 + l < cnt) ? mk[64 + l] : 0ull;
    int ra = 0, rb = 0;
    for (int t = 0; t < cnt; ++t) {
        unsigned long long kt = mk[t];               // uniform LDS broadcast
        ra += (kt > va);
        rb += (kt > vb);
    }
    if (l < cnt) mk[ra] = va;
    if (64 + l < cnt) mk[rb] = vb;

    // fetch member boxes (sorted order)
    for (int t = l; t < cnt; t += 64) {
        int i = (int)(~(unsigned int)mk[t]);
        mbox[t] = bxs[i];
    }

    // chunk 0: ballot fixpoint == greedy (validated exact)
    unsigned long long kept0 = 0ull;
    {
        bool act = (l < cnt);
        float4 a = mbox[act ? l : 0];
        float aarea = (a.z - a.x) * (a.w - a.y);
        unsigned long long colmask = 0ull;
        int tend = min(64, cnt);
        for (int t = 0; t < tend; ++t) {
            float4 tb = mbox[t];                     // uniform LDS broadcast
            if (t < l && act && iou_gt_thr(a, aarea, tb)) colmask |= (1ull << t);
        }
        unsigned long long kept = __ballot(act);
        while (true) {
            bool alive = act && ((colmask & kept) == 0ull);
            unsigned long long k2m = __ballot(alive);
            if (k2m == kept) break;
            kept = k2m;
        }
        kept0 = kept;
        bool alive = act && ((colmask & kept0) == 0ull);
        if (alive) {
            unsigned long long myk = mk[l];
            keysrc[(size_t)b * NN + (int)(~(unsigned int)myk)] = myk;
        }
    }
    // chunk 1 (members 64..cnt-1): rare
    if (cnt > 64) {
        int m = 64 + l;
        bool act = (m < cnt);
        float4 a = mbox[act ? m : 0];
        float aarea = (a.z - a.x) * (a.w - a.y);
        bool presup = false;
        for (int t = 0; t < 64; ++t) {
            if ((kept0 >> t) & 1ull) {
                if (act && iou_gt_thr(a, aarea, mbox[t])) presup = true;
            }
        }
        unsigned long long colmask = 0ull;
        for (int t = 64; t < cnt; ++t) {
            float4 tb = mbox[t];
            if ((t - 64) < l && act && iou_gt_thr(a, aarea, tb)) colmask |= (1ull << (t - 64));
        }
        bool pre = act && !presup;
        unsigned long long kept = __ballot(pre);
        while (true) {
            bool alive = pre && ((colmask & kept) == 0ull);
            unsigned long long k2m = __ballot(alive);
            if (k2m == kept) break;
            kept = k2m;
        }
        bool alive = pre && ((colmask & kept) == 0ull);
        if (alive) {
            unsigned long long myk = mk[64 + l];
            keysrc[(size_t)b * NN + (int)(~(unsigned int)myk)] = myk;
        }
    }
}

// ---- kC: 1 block per batch x 1024. Positional keys from keysrc (coalesced),
// histogram threshold, candidate rank-count, write. (R14/R18-validated; dead
// Tcnt counting removed — empty-hist path already yields zero writes.) ----
__global__ void __launch_bounds__(1024) kC_emit(
        const unsigned long long* __restrict__ keysrc,
        const float* __restrict__ boxes,
        const int* __restrict__ cls,
        float* __restrict__ out) {
    const int b = blockIdx.x;
    const int tid = threadIdx.x;
    const int wv = tid >> 6;
    const int l = tid & 63;

    __shared__ ulonglong2 keys2[1024];               // 16 KB (positional by row)
    __shared__ ulonglong2 cand2[256];                //  4 KB
    __shared__ int hist[256];
    __shared__ int tbsh, candn;
    unsigned long long* keys = (unsigned long long*)keys2;
    unsigned long long* cand = (unsigned long long*)cand2;

    if (tid < 256) hist[tid] = 0;
    if (tid < 48) keys[2000 + tid] = 0ull;           // pad tail
    if (tid == 0) candn = 0;
    __syncthreads();

    const float4* bxs = (const float4*)boxes + (size_t)b * NN;

    // load keys positionally + histogram (2 coalesced iterations)
    for (int i = tid; i < NN; i += 1024) {
        unsigned long long kv = keysrc[(size_t)b * NN + i];
        keys[i] = kv;
        if (kv != 0ull) atomicAdd(&hist[(int)((kv >> 47) & 0xFF)], 1);
    }
    __syncthreads();

    // wave 0: threshold bucket tb (kept scores in [0.7,1) -> fixed exponent ->
    // bucket (key>>47)&0xFF monotone in score)
    if (wv == 0) {
        int cum = 0, tb = 0, done = 0;
        for (int chunk = 3; chunk >= 0 && !done; --chunk) {
            int bkt = chunk * 64 + (63 - l);         // lane 0 = highest bucket
            int s = hist[bkt];
            #pragma unroll
            for (int off = 1; off < 64; off <<= 1) {
                int o = __shfl_up(s, off);
                if (l >= off) s += o;
            }
            int chunktot = __shfl(s, 63);
            if (cum + chunktot >= MAXI) {
                unsigned long long m = __ballot(cum + s >= MAXI);
                int lane = __ffsll((long long)m) - 1;
                tb = chunk * 64 + (63 - lane);
                done = 1;
            } else {
                cum += chunktot;
            }
        }
        if (l == 0) tbsh = done ? tb : 0;            // T<100 -> all buckets
    }
    __syncthreads();
    const int tb = tbsh;

    // compact candidates (bucket >= tb); rank among candidates == global rank
    for (int i = tid; i < NN; i += 1024) {
        unsigned long long kv = keys[i];
        bool pr = (kv != 0ull) && ((int)((kv >> 47) & 0xFF) >= tb);
        unsigned long long m = __ballot(pr);
        int basew = 0;
        if (l == 0 && m) basew = atomicAdd(&candn, __popcll(m));
        basew = __shfl(basew, 0);
        if (pr) {
            int pos = basew + __popcll(m & ((1ull << l) - 1ull));
            if (pos < 512) cand[pos] = kv;
        }
    }
    __syncthreads();
    const int nc = candn;
    if (tid == 0 && nc < 512) cand[nc] = 0ull;       // pad for pair read
    __syncthreads();

    if (nc <= 512) {
        const int np = (nc + 1) >> 1;
        for (int s = tid; s < nc; s += 1024) {
            unsigned long long myk = cand[s];
            int r = 0;
            for (int t = 0; t < np; ++t) {
                ulonglong2 kv = cand2[t];
                r += (int)(kv.x > myk);
                r += (int)(kv.y > myk);              // pad 0 never counts
            }
            if (r < MAXI) {
                int i = (int)(~(unsigned int)myk);
                float4 bx = bxs[i];
                float* o = out + ((size_t)b * MAXI + r) * 6;
                o[0] = bx.x; o[1] = bx.y; o[2] = bx.z; o[3] = bx.w;
                o[4] = (float)cls[(size_t)b * NN + i];
                o[5] = __uint_as_float((unsigned int)(myk >> 32));
            }
        }
    } else {
        // pathological fallback: rank over all rows (zeros excluded)
        for (int s = tid; s < NN; s += 1024) {
            unsigned long long myk = keys[s];
            if (myk == 0ull) continue;
            int r = 0;
            for (int t = 0; t < 1024; ++t) {
                ulonglong2 kv = keys2[t];
                r += (int)(kv.x > myk);
                r += (int)(kv.y > myk);
            }
            if (r < MAXI) {
                int i = (int)(~(unsigned int)myk);
                float4 bx = bxs[i];
                float* o = out + ((size_t)b * MAXI + r) * 6;
                o[0] = bx.x; o[1] = bx.y; o[2] = bx.z; o[3] = bx.w;
                o[4] = (float)cls[(size_t)b * NN + i];
                o[5] = __uint_as_float((unsigned int)(myk >> 32));
            }
        }
    }
}

extern "C" void kernel_launch(void* const* d_in, const int* in_sizes, int n_in,
                              void* d_out, int out_size, void* d_ws, size_t ws_size,
                              hipStream_t stream) {
    const float* rois   = (const float*)d_in[0];
    const float* probs  = (const float*)d_in[1];
    const float* deltas = (const float*)d_in[2];
    float* outp = (float*)d_out;

    char* ws = (char*)d_ws;
    float* boxes = (float*)(ws + 0);
    float* sc    = (float*)(ws + 256000);
    int*   cls   = (int*)  (ws + 320000);
    int*   qcnt  = (int*)  (ws + 384000);
    unsigned long long* cslot  = (unsigned long long*)(ws + 394240);
    unsigned long long* keysrc = (unsigned long long*)(ws + 1049600);

    {
        int blocks = (BB * NN * 64) / 256;   // one wave per ROI, exact (WIDE)
        kA_refine<<<blocks, 256, 0, stream>>>(rois, probs, deltas, boxes, sc,
                                              cls, keysrc, outp);
    }
    kB0_bucket<<<BB * 4, 1024, 0, stream>>>(sc, cls, qcnt, cslot);
    kB1_nms<<<BB * NCLS, 64, 0, stream>>>(boxes, qcnt, cslot, keysrc);
    kC_emit<<<BB, 1024, 0, stream>>>(keysrc, boxes, cls, outp);
}